// Round 17
// baseline (275.558 us; speedup 1.0000x reference)
//
#include <hip/hip_runtime.h>
#include <math.h>

#define N_NODES 10000
#define F_IN_D  256
#define H_DIM   128
#define C_OUTD  40
#define NHEADS  8
#define NEDGES  160000
#define ETOT    (NEDGES + N_NODES)
#define SCALE_F 0.25f  /* 1/sqrt(16) */
#define TILES_N 157    /* ceil(10000/64) */

typedef __attribute__((ext_vector_type(8))) short bf16x8;   // 8 bf16 = 4 VGPRs
typedef __attribute__((ext_vector_type(4))) float f32x4;
typedef __attribute__((ext_vector_type(2))) float f32x2;

__device__ __forceinline__ unsigned short f2bf(float f) {
    unsigned int u = __float_as_uint(f);
    unsigned int r = (u + 0x7FFFu + ((u >> 16) & 1u)) >> 16;  // RNE
    return (unsigned short)r;
}
__device__ __forceinline__ float bf2f(unsigned short h) {
    return __uint_as_float(((unsigned int)h) << 16);
}
__device__ __forceinline__ unsigned char f2fp8(float v) {
    int pk = __builtin_amdgcn_cvt_pk_fp8_f32(v, v, 0, false);  // OCP e4m3fn
    return (unsigned char)(pk & 0xff);
}

// ---------------- graph preprocessing ----------------

__global__ void k_deg_count(const int* __restrict__ col, int* degi) {
    int e = blockIdx.x * 256 + threadIdx.x;
    if (e < NEDGES) atomicAdd(&degi[col[e]], 1);
}

__global__ void k_scan(const int* __restrict__ degi, int* offsets, int* cursor) {
    __shared__ int part[256];
    int tid = threadIdx.x;
    int s = 0;
    if (tid < 250) {
        const int4* d4 = (const int4*)degi;
        for (int i = 0; i < 10; ++i) {
            int4 v = d4[tid * 10 + i];
            s += v.x + v.y + v.z + v.w;
        }
    }
    part[tid] = s;
    __syncthreads();
    for (int off = 1; off < 256; off <<= 1) {
        int v = 0;
        if (tid >= off) v = part[tid - off];
        __syncthreads();
        part[tid] += v;
        __syncthreads();
    }
    if (tid < 250) {
        int base = part[tid] - s;  // exclusive prefix
        int beg = tid * 40;
        for (int i = 0; i < 40; ++i) {
            offsets[beg + i] = base;
            cursor[beg + i]  = 0;
            base += degi[beg + i];
        }
    }
}

__global__ void k_scatter(const int* __restrict__ row, const int* __restrict__ col,
                          const int* __restrict__ degi, const int* __restrict__ offsets,
                          int* cursor, int* csr_row, float* csr_norm) {
    int e = blockIdx.x * 256 + threadIdx.x;
    if (e >= ETOT) return;
    int r, c;
    if (e < NEDGES) { r = row[e]; c = col[e]; }
    else            { r = c = e - NEDGES; }   // self-loop
    int slot = offsets[c] + atomicAdd(&cursor[c], 1);
    float dr = rsqrtf((float)degi[r]);
    float dc = rsqrtf((float)degi[c]);
    csr_row[slot]  = r;
    csr_norm[slot] = dr * dc;
}

// ---------------- fused prep: weight casts + deg_init ----------------

__global__ void k_prep(const float* __restrict__ w1, const float* __restrict__ wq,
                       const float* __restrict__ wk, const float* __restrict__ wv,
                       const float* __restrict__ w2,
                       unsigned short* __restrict__ W1T, unsigned short* __restrict__ WTq,
                       unsigned short* __restrict__ WTk, unsigned short* __restrict__ WTv,
                       unsigned short* __restrict__ W2T, int* __restrict__ degi) {
    int b = blockIdx.x;
    if (b < 728) {
        int e = b * 256 + threadIdx.x;
        if (e < 32768) {
            int n = e >> 8, k = e & 255;
            W1T[e] = f2bf(w1[k * H_DIM + n]);
        } else if (e < 180224) {
            int e2 = e - 32768;
            int mat = e2 >> 14;          // 0..8
            int r   = e2 & 16383;
            int n = r >> 7, k = r & 127;
            int l = mat / 3, ws = mat % 3;
            const float*    src = (ws == 0) ? wq  : (ws == 1) ? wk  : wv;
            unsigned short* dst = (ws == 0) ? WTq : (ws == 1) ? WTk : WTv;
            dst[l * 16384 + n * H_DIM + k] = f2bf(src[l * 16384 + k * H_DIM + n]);
        } else if (e < 186368) {
            int e3 = e - 180224;
            int c = e3 >> 7, k = e3 & 127;
            W2T[c * H_DIM + k] = (c < C_OUTD) ? f2bf(w2[k * C_OUTD + c]) : 0;
        }
    } else {
        int i = (b - 728) * 256 + threadIdx.x;
        if (i < N_NODES) degi[i] = 1;    // self-loop
    }
}

// ---------------- MFMA lin1: X0 = relu(x @ W1 + b1), fp32 in, bf16 out ---------
// Reads x_param fp32 directly (cast fused). rowA CLAMPED (input buffer).
// nct RUNTIME arg (=8): prevents full-unroll spill.

__global__ __launch_bounds__(256) void k_lin1_mfma(const float* __restrict__ X,
                                                   const unsigned short* __restrict__ W1T,
                                                   const float* __restrict__ b1,
                                                   unsigned short* __restrict__ X0,
                                                   int nct) {
    int tid = threadIdx.x;
    int wid = tid >> 6, lane = tid & 63;
    int m = lane & 15, quad = lane >> 4;
    int rowA = blockIdx.x * 64 + wid * 16 + m;
    int rowc = rowA < N_NODES ? rowA : N_NODES - 1;
    bf16x8 af[8];
    const float* ap = X + (size_t)rowc * F_IN_D + quad * 8;
    #pragma unroll
    for (int s = 0; s < 8; ++s) {
        float4 lo = *(const float4*)(ap + s * 32);
        float4 hi = *(const float4*)(ap + s * 32 + 4);
        union { unsigned short u[8]; bf16x8 v; } pk;
        pk.u[0] = f2bf(lo.x); pk.u[1] = f2bf(lo.y);
        pk.u[2] = f2bf(lo.z); pk.u[3] = f2bf(lo.w);
        pk.u[4] = f2bf(hi.x); pk.u[5] = f2bf(hi.y);
        pk.u[6] = f2bf(hi.z); pk.u[7] = f2bf(hi.w);
        af[s] = pk.v;
    }
    int row0 = blockIdx.x * 64 + wid * 16 + quad * 4;
    for (int ct = 0; ct < nct; ++ct) {
        int col = ct * 16 + m;
        const unsigned short* bp = W1T + (size_t)col * F_IN_D + quad * 8;
        f32x4 acc = {0.f, 0.f, 0.f, 0.f};
        #pragma unroll
        for (int s = 0; s < 8; ++s) {
            bf16x8 bfr = __builtin_bit_cast(bf16x8, *(const uint4*)(bp + s * 32));
            acc = __builtin_amdgcn_mfma_f32_16x16x32_bf16(af[s], bfr, acc, 0, 0, 0);
        }
        float bb = b1[col];
        #pragma unroll
        for (int rg = 0; rg < 4; ++rg) {
            int r = row0 + rg;
            if (r < N_NODES)
                X0[(size_t)r * H_DIM + col] = f2bf(fmaxf(acc[rg] + bb, 0.f));
        }
    }
}

// ---------------- MFMA fused QKV projection (K+V share A-frags) ----------------
// grid = (1+t)*TILES_N; mi 0 = Q (bf16 out, dual-col chains); mi 1..t = K AND V
// for slice mi-1 (dual K/V chains share one A-load -- halves A fetch).
// K/V: fp8 e4m3, layout [node][slice(3)][128].
// nq RUNTIME (=4): Q does nq col-pairs, KV does 2*nq cols. Loop form kept
// (full B-preload REGRESSED +11 us in R13/R14).

__global__ __launch_bounds__(256) void k_qkv_mfma(const unsigned short* __restrict__ XHb,
                                                  const unsigned short* __restrict__ WTq,
                                                  const unsigned short* __restrict__ WTk,
                                                  const unsigned short* __restrict__ WTv,
                                                  const float* __restrict__ bq,
                                                  const float* __restrict__ bk,
                                                  const float* __restrict__ bv,
                                                  unsigned short* __restrict__ Qb,
                                                  unsigned char* __restrict__ Kb,
                                                  unsigned char* __restrict__ Vb,
                                                  int l, int t, int nq) {
    int tid = threadIdx.x;
    int wid = tid >> 6, lane = tid & 63;
    int m = lane & 15, quad = lane >> 4;
    int mi = blockIdx.x / TILES_N;
    int rt = blockIdx.x % TILES_N;
    int slice = (mi == 0) ? l : (mi - 1);
    const unsigned short* A = XHb + (size_t)slice * N_NODES * H_DIM;
    int rowA = rt * 64 + wid * 16 + m;
    bf16x8 af[4];
    const unsigned short* ap = A + (size_t)rowA * H_DIM + quad * 8;
    #pragma unroll
    for (int s = 0; s < 4; ++s)
        af[s] = __builtin_bit_cast(bf16x8, *(const uint4*)(ap + s * 32));
    int row0 = rt * 64 + wid * 16 + quad * 4;

    if (mi == 0) {
        // Q: dual-col accumulator interleave
        for (int cp = 0; cp < nq; ++cp) {
            int colA = cp * 32 + m;
            int colB = colA + 16;
            const unsigned short* bpA = WTq + (size_t)colA * H_DIM + quad * 8;
            const unsigned short* bpB = WTq + (size_t)colB * H_DIM + quad * 8;
            bf16x8 bA[4], bB[4];
            #pragma unroll
            for (int s = 0; s < 4; ++s) {
                bA[s] = __builtin_bit_cast(bf16x8, *(const uint4*)(bpA + s * 32));
                bB[s] = __builtin_bit_cast(bf16x8, *(const uint4*)(bpB + s * 32));
            }
            f32x4 accA = {0.f, 0.f, 0.f, 0.f};
            f32x4 accB = {0.f, 0.f, 0.f, 0.f};
            #pragma unroll
            for (int s = 0; s < 4; ++s) {
                accA = __builtin_amdgcn_mfma_f32_16x16x32_bf16(af[s], bA[s], accA, 0, 0, 0);
                accB = __builtin_amdgcn_mfma_f32_16x16x32_bf16(af[s], bB[s], accB, 0, 0, 0);
            }
            float bbA = bq[colA], bbB = bq[colB];
            #pragma unroll
            for (int rg = 0; rg < 4; ++rg) {
                int r = row0 + rg;
                if (r < N_NODES) {
                    Qb[(size_t)r * H_DIM + colA] = f2bf(accA[rg] + bbA);
                    Qb[(size_t)r * H_DIM + colB] = f2bf(accB[rg] + bbB);
                }
            }
        }
    } else {
        // K and V for this slice: dual K/V chains per col tile
        int ncols = 2 * nq;
        for (int ct = 0; ct < ncols; ++ct) {
            int col = ct * 16 + m;
            const unsigned short* bpK = WTk + (size_t)col * H_DIM + quad * 8;
            const unsigned short* bpV = WTv + (size_t)col * H_DIM + quad * 8;
            bf16x8 bK[4], bV[4];
            #pragma unroll
            for (int s = 0; s < 4; ++s) {
                bK[s] = __builtin_bit_cast(bf16x8, *(const uint4*)(bpK + s * 32));
                bV[s] = __builtin_bit_cast(bf16x8, *(const uint4*)(bpV + s * 32));
            }
            f32x4 accK = {0.f, 0.f, 0.f, 0.f};
            f32x4 accV = {0.f, 0.f, 0.f, 0.f};
            #pragma unroll
            for (int s = 0; s < 4; ++s) {
                accK = __builtin_amdgcn_mfma_f32_16x16x32_bf16(af[s], bK[s], accK, 0, 0, 0);
                accV = __builtin_amdgcn_mfma_f32_16x16x32_bf16(af[s], bV[s], accV, 0, 0, 0);
            }
            float bbK = bk[col], bbV = bv[col];
            #pragma unroll
            for (int rg = 0; rg < 4; ++rg) {
                int r = row0 + rg;
                if (r < N_NODES) {
                    size_t base = ((size_t)r * 3 + slice) * H_DIM + col;
                    Kb[base] = f2fp8(accK[rg] + bbK);
                    Vb[base] = f2fp8(accV[rg] + bbV);
                }
            }
        }
    }
}

// ---------------- fused per-node attention aggregation (wave-per-node) ----------------
// 256 threads = 4 waves = 4 nodes. fp8 K/V, 8 dims/lane (uint2), 16 lanes per
// edge -> FOUR edges per wave-iteration (quarter = lane>>4).
// L2F: final layer fuses lin2+log_softmax in the epilogue (X3 never stored;
// X row round-trips 2 KB LDS, lane c<40 computes its class dot vs W2T in L2).
// NOTE: R13's manual software pipeline REGRESSED -- keep plain loop form.

template <int T, bool L2F>
__global__ __launch_bounds__(256) void k_attn_agg(const unsigned short* __restrict__ Q,
                                                  const unsigned int* __restrict__ K,
                                                  const unsigned int* __restrict__ V,
                                                  const int* __restrict__ csr_row,
                                                  const float* __restrict__ csr_norm,
                                                  const int* __restrict__ offsets,
                                                  const int* __restrict__ degi,
                                                  unsigned int* __restrict__ Xout,
                                                  const unsigned short* __restrict__ W2T,
                                                  const float* __restrict__ b2,
                                                  float* __restrict__ out) {
    __shared__ float xrow[4][128];
    int tid = threadIdx.x;
    int wid = tid >> 6, lane = tid & 63;
    int quarter = lane >> 4, ci = lane & 15;
    int n = blockIdx.x * 4 + wid;        // grid 2500*4 == N_NODES exactly
    float q[8];
    {
        uint4 qp = *(const uint4*)&Q[(size_t)n * H_DIM + ci * 8];
        q[0] = __uint_as_float(qp.x << 16) * SCALE_F;
        q[1] = __uint_as_float(qp.x & 0xffff0000u) * SCALE_F;
        q[2] = __uint_as_float(qp.y << 16) * SCALE_F;
        q[3] = __uint_as_float(qp.y & 0xffff0000u) * SCALE_F;
        q[4] = __uint_as_float(qp.z << 16) * SCALE_F;
        q[5] = __uint_as_float(qp.z & 0xffff0000u) * SCALE_F;
        q[6] = __uint_as_float(qp.w << 16) * SCALE_F;
        q[7] = __uint_as_float(qp.w & 0xffff0000u) * SCALE_F;
    }
    int start = offsets[n];
    int cnt   = degi[n];
    int nq = (cnt + 3) >> 2;
    float a[8];
    #pragma unroll
    for (int i = 0; i < 8; ++i) a[i] = 0.f;

    for (int j = 0; j < nq; ++j) {
        int j4 = j * 4 + quarter;
        int valid = j4 < cnt;
        int idx = start + (valid ? j4 : 0);
        int   r   = csr_row[idx];
        float nrm = valid ? csr_norm[idx] : 0.f;
        const uint2* kp = (const uint2*)&K[(size_t)r * 96 + ci * 2];
        const uint2* vp = (const uint2*)&V[(size_t)r * 96 + ci * 2];
        uint2 kw[T], vw[T];
        #pragma unroll
        for (int s = 0; s < T; ++s) { kw[s] = kp[s * 16]; vw[s] = vp[s * 16]; }
        float sc[T];
        #pragma unroll
        for (int s = 0; s < T; ++s) {
            f32x2 k0 = __builtin_amdgcn_cvt_pk_f32_fp8(kw[s].x, false);
            f32x2 k1 = __builtin_amdgcn_cvt_pk_f32_fp8(kw[s].x, true);
            f32x2 k2 = __builtin_amdgcn_cvt_pk_f32_fp8(kw[s].y, false);
            f32x2 k3 = __builtin_amdgcn_cvt_pk_f32_fp8(kw[s].y, true);
            float p = q[0] * k0[0] + q[1] * k0[1] + q[2] * k1[0] + q[3] * k1[1]
                    + q[4] * k2[0] + q[5] * k2[1] + q[6] * k3[0] + q[7] * k3[1];
            p += __shfl_xor(p, 1, 2);    // head = ci>>1: pair-reduce
            sc[s] = p;
        }
        float m = 0.f;
        #pragma unroll
        for (int s = 0; s < T; ++s) m = fmaxf(m, sc[s]);
        float den = __expf(-m);          // restricted-softmax null slot
        float mv[8];
        #pragma unroll
        for (int i = 0; i < 8; ++i) mv[i] = 0.f;
        #pragma unroll
        for (int s = 0; s < T; ++s) {
            float w = __expf(sc[s] - m);
            den += w;
            f32x2 v0 = __builtin_amdgcn_cvt_pk_f32_fp8(vw[s].x, false);
            f32x2 v1 = __builtin_amdgcn_cvt_pk_f32_fp8(vw[s].x, true);
            f32x2 v2 = __builtin_amdgcn_cvt_pk_f32_fp8(vw[s].y, false);
            f32x2 v3 = __builtin_amdgcn_cvt_pk_f32_fp8(vw[s].y, true);
            mv[0] += w * v0[0]; mv[1] += w * v0[1];
            mv[2] += w * v1[0]; mv[3] += w * v1[1];
            mv[4] += w * v2[0]; mv[5] += w * v2[1];
            mv[6] += w * v3[0]; mv[7] += w * v3[1];
        }
        float ws = __fdividef(nrm, den);
        #pragma unroll
        for (int i = 0; i < 8; ++i) a[i] += ws * mv[i];
    }
    // combine the four edge-quarters
    #pragma unroll
    for (int i = 0; i < 8; ++i) {
        a[i] += __shfl_xor(a[i], 16, 64);
        a[i] += __shfl_xor(a[i], 32, 64);
    }

    if (!L2F) {
        if (quarter == 0) {
            uint4 o;
            o.x = ((unsigned int)f2bf(fmaxf(a[1], 0.f)) << 16) | (unsigned int)f2bf(fmaxf(a[0], 0.f));
            o.y = ((unsigned int)f2bf(fmaxf(a[3], 0.f)) << 16) | (unsigned int)f2bf(fmaxf(a[2], 0.f));
            o.z = ((unsigned int)f2bf(fmaxf(a[5], 0.f)) << 16) | (unsigned int)f2bf(fmaxf(a[4], 0.f));
            o.w = ((unsigned int)f2bf(fmaxf(a[7], 0.f)) << 16) | (unsigned int)f2bf(fmaxf(a[6], 0.f));
            *(uint4*)&Xout[(size_t)n * 64 + ci * 4] = o;   // relu, packed bf16
        }
    } else {
        // fused lin2 + log_softmax; X3 never materialized
        if (quarter == 0) {
            #pragma unroll
            for (int i = 0; i < 8; ++i) xrow[wid][ci * 8 + i] = fmaxf(a[i], 0.f);
        }
        __syncthreads();
        const float* xr = xrow[wid];
        int c = lane;
        int cw = (c < 48) ? c : 0;
        const unsigned short* wr = W2T + (size_t)cw * H_DIM;
        float acc = (c < C_OUTD) ? b2[c] : 0.f;
        for (int k0 = 0; k0 < H_DIM; k0 += 8) {
            uint4 wv4 = *(const uint4*)(wr + k0);
            float4 x0 = *(const float4*)&xr[k0];
            float4 x1 = *(const float4*)&xr[k0 + 4];
            acc += x0.x * __uint_as_float(wv4.x << 16)
                 + x0.y * __uint_as_float(wv4.x & 0xffff0000u)
                 + x0.z * __uint_as_float(wv4.y << 16)
                 + x0.w * __uint_as_float(wv4.y & 0xffff0000u)
                 + x1.x * __uint_as_float(wv4.z << 16)
                 + x1.y * __uint_as_float(wv4.z & 0xffff0000u)
                 + x1.z * __uint_as_float(wv4.w << 16)
                 + x1.w * __uint_as_float(wv4.w & 0xffff0000u);
        }
        float lg = (c < C_OUTD) ? acc : -INFINITY;
        float mx = lg;
        #pragma unroll
        for (int o = 32; o > 0; o >>= 1) mx = fmaxf(mx, __shfl_xor(mx, o, 64));
        float e = (c < C_OUTD) ? __expf(lg - mx) : 0.f;
        float sm = e;
        #pragma unroll
        for (int o = 32; o > 0; o >>= 1) sm += __shfl_xor(sm, o, 64);
        float lse = mx + __logf(sm);
        if (c < C_OUTD) out[(size_t)n * C_OUTD + c] = lg - lse;
    }
}

// ---------------- launcher ----------------

extern "C" void kernel_launch(void* const* d_in, const int* in_sizes, int n_in,
                              void* d_out, int out_size, void* d_ws, size_t ws_size,
                              hipStream_t stream) {
    const int*   ei      = (const int*)d_in[0];
    const int*   row     = ei;
    const int*   col     = ei + NEDGES;
    const float* x_param = (const float*)d_in[1];
    const float* lin1_w  = (const float*)d_in[2];
    const float* lin1_b  = (const float*)d_in[3];
    const float* wq      = (const float*)d_in[4];
    const float* wk      = (const float*)d_in[5];
    const float* wv      = (const float*)d_in[6];
    const float* bq      = (const float*)d_in[7];
    const float* bk      = (const float*)d_in[8];
    const float* bv      = (const float*)d_in[9];
    const float* lin2_w  = (const float*)d_in[10];
    const float* lin2_b  = (const float*)d_in[11];
    float*       out     = (float*)d_out;

    char* wbase = (char*)d_ws;
    size_t off = 0;
    auto alloc = [&](size_t bytes) -> void* {
        off = (off + 255) & ~(size_t)255;
        void* p = wbase + off;
        off += bytes;
        return p;
    };
    int*            degi     = (int*)           alloc((size_t)N_NODES * 4);
    int*            offsets  = (int*)           alloc((size_t)N_NODES * 4);
    int*            cursor   = (int*)           alloc((size_t)N_NODES * 4);
    int*            csr_row  = (int*)           alloc((size_t)ETOT * 4);
    float*          csr_norm = (float*)         alloc((size_t)ETOT * 4);
    unsigned short* W1T      = (unsigned short*)alloc((size_t)H_DIM * F_IN_D * 2);
    unsigned short* WTq      = (unsigned short*)alloc((size_t)3 * H_DIM * H_DIM * 2);
    unsigned short* WTk      = (unsigned short*)alloc((size_t)3 * H_DIM * H_DIM * 2);
    unsigned short* WTv      = (unsigned short*)alloc((size_t)3 * H_DIM * H_DIM * 2);
    unsigned short* W2T      = (unsigned short*)alloc((size_t)48 * H_DIM * 2);
    unsigned short* XHb      = (unsigned short*)alloc((size_t)4 * N_NODES * H_DIM * 2);
    unsigned short* Qb       = (unsigned short*)alloc((size_t)N_NODES * H_DIM * 2);
    unsigned char*  Kb       = (unsigned char*) alloc((size_t)N_NODES * 3 * H_DIM);
    unsigned char*  Vb       = (unsigned char*) alloc((size_t)N_NODES * 3 * H_DIM);

    // fused prep: weight casts + deg init
    k_prep<<<768, 256, 0, stream>>>(lin1_w, wq, wk, wv, lin2_w,
                                    W1T, WTq, WTk, WTv, W2T, degi);
    k_deg_count<<<(NEDGES + 255) / 256, 256, 0, stream>>>(col, degi);
    k_scan     <<<1, 256, 0, stream>>>(degi, offsets, cursor);
    k_scatter  <<<(ETOT + 255) / 256, 256, 0, stream>>>(row, col, degi, offsets, cursor,
                                                        csr_row, csr_norm);

    // x0 = relu(x @ W1 + b1)  [MFMA, fp32 in (cast fused), bf16 out]
    k_lin1_mfma<<<TILES_N, 256, 0, stream>>>(x_param, W1T, lin1_b, XHb, 8);

    for (int l = 0; l < 3; ++l) {
        int t = l + 1;
        k_qkv_mfma<<<(1 + t) * TILES_N, 256, 0, stream>>>(
            XHb, WTq + (size_t)l * 16384, WTk + (size_t)l * 16384, WTv + (size_t)l * 16384,
            bq + l * H_DIM, bk + l * H_DIM, bv + l * H_DIM,
            Qb, Kb, Vb, l, t, 4);
        unsigned int* Xnext = (unsigned int*)(XHb + (size_t)(l + 1) * N_NODES * H_DIM);
        if (t == 1)
            k_attn_agg<1, false><<<2500, 256, 0, stream>>>(
                Qb, (const unsigned int*)Kb, (const unsigned int*)Vb, csr_row,
                csr_norm, offsets, degi, Xnext, W2T, lin2_b, out);
        else if (t == 2)
            k_attn_agg<2, false><<<2500, 256, 0, stream>>>(
                Qb, (const unsigned int*)Kb, (const unsigned int*)Vb, csr_row,
                csr_norm, offsets, degi, Xnext, W2T, lin2_b, out);
        else
            k_attn_agg<3, true><<<2500, 256, 0, stream>>>(
                Qb, (const unsigned int*)Kb, (const unsigned int*)Vb, csr_row,
                csr_norm, offsets, degi, Xnext, W2T, lin2_b, out);
    }
}

// Round 18
// 267.506 us; speedup vs baseline: 1.0301x; 1.0301x over previous
//
#include <hip/hip_runtime.h>
#include <math.h>

#define N_NODES 10000
#define F_IN_D  256
#define H_DIM   128
#define C_OUTD  40
#define NHEADS  8
#define NEDGES  160000
#define ETOT    (NEDGES + N_NODES)
#define SCALE_F 0.25f  /* 1/sqrt(16) */
#define TILES_N 157    /* ceil(10000/64) */

typedef __attribute__((ext_vector_type(8))) short bf16x8;   // 8 bf16 = 4 VGPRs
typedef __attribute__((ext_vector_type(4))) float f32x4;
typedef __attribute__((ext_vector_type(2))) float f32x2;

__device__ __forceinline__ unsigned short f2bf(float f) {
    unsigned int u = __float_as_uint(f);
    unsigned int r = (u + 0x7FFFu + ((u >> 16) & 1u)) >> 16;  // RNE
    return (unsigned short)r;
}
__device__ __forceinline__ float bf2f(unsigned short h) {
    return __uint_as_float(((unsigned int)h) << 16);
}
__device__ __forceinline__ unsigned char f2fp8(float v) {
    int pk = __builtin_amdgcn_cvt_pk_fp8_f32(v, v, 0, false);  // OCP e4m3fn
    return (unsigned char)(pk & 0xff);
}

// ---------------- graph preprocessing ----------------

__global__ void k_deg_count(const int* __restrict__ col, int* degi) {
    int e = blockIdx.x * 256 + threadIdx.x;
    if (e < NEDGES) atomicAdd(&degi[col[e]], 1);
}

__global__ void k_scan(const int* __restrict__ degi, int* offsets, int* cursor) {
    __shared__ int part[256];
    int tid = threadIdx.x;
    int s = 0;
    if (tid < 250) {
        const int4* d4 = (const int4*)degi;
        for (int i = 0; i < 10; ++i) {
            int4 v = d4[tid * 10 + i];
            s += v.x + v.y + v.z + v.w;
        }
    }
    part[tid] = s;
    __syncthreads();
    for (int off = 1; off < 256; off <<= 1) {
        int v = 0;
        if (tid >= off) v = part[tid - off];
        __syncthreads();
        part[tid] += v;
        __syncthreads();
    }
    if (tid < 250) {
        int base = part[tid] - s;  // exclusive prefix
        int beg = tid * 40;
        for (int i = 0; i < 40; ++i) {
            offsets[beg + i] = base;
            cursor[beg + i]  = 0;
            base += degi[beg + i];
        }
    }
}

__global__ void k_scatter(const int* __restrict__ row, const int* __restrict__ col,
                          const int* __restrict__ degi, const int* __restrict__ offsets,
                          int* cursor, int* csr_row, float* csr_norm) {
    int e = blockIdx.x * 256 + threadIdx.x;
    if (e >= ETOT) return;
    int r, c;
    if (e < NEDGES) { r = row[e]; c = col[e]; }
    else            { r = c = e - NEDGES; }   // self-loop
    int slot = offsets[c] + atomicAdd(&cursor[c], 1);
    float dr = rsqrtf((float)degi[r]);
    float dc = rsqrtf((float)degi[c]);
    csr_row[slot]  = r;
    csr_norm[slot] = dr * dc;
}

// ---------------- fused prep: weight casts + deg_init ----------------

__global__ void k_prep(const float* __restrict__ w1, const float* __restrict__ wq,
                       const float* __restrict__ wk, const float* __restrict__ wv,
                       const float* __restrict__ w2,
                       unsigned short* __restrict__ W1T, unsigned short* __restrict__ WTq,
                       unsigned short* __restrict__ WTk, unsigned short* __restrict__ WTv,
                       unsigned short* __restrict__ W2T, int* __restrict__ degi) {
    int b = blockIdx.x;
    if (b < 728) {
        int e = b * 256 + threadIdx.x;
        if (e < 32768) {
            int n = e >> 8, k = e & 255;
            W1T[e] = f2bf(w1[k * H_DIM + n]);
        } else if (e < 180224) {
            int e2 = e - 32768;
            int mat = e2 >> 14;          // 0..8
            int r   = e2 & 16383;
            int n = r >> 7, k = r & 127;
            int l = mat / 3, ws = mat % 3;
            const float*    src = (ws == 0) ? wq  : (ws == 1) ? wk  : wv;
            unsigned short* dst = (ws == 0) ? WTq : (ws == 1) ? WTk : WTv;
            dst[l * 16384 + n * H_DIM + k] = f2bf(src[l * 16384 + k * H_DIM + n]);
        } else if (e < 186368) {
            int e3 = e - 180224;
            int c = e3 >> 7, k = e3 & 127;
            W2T[c * H_DIM + k] = (c < C_OUTD) ? f2bf(w2[k * C_OUTD + c]) : 0;
        }
    } else {
        int i = (b - 728) * 256 + threadIdx.x;
        if (i < N_NODES) degi[i] = 1;    // self-loop
    }
}

// ---------------- MFMA lin1: X0 = relu(x @ W1 + b1), fp32 in, bf16 out ---------
// Reads x_param fp32 directly (cast fused). rowA CLAMPED (input buffer).
// nct RUNTIME arg (=8): prevents full-unroll spill.

__global__ __launch_bounds__(256) void k_lin1_mfma(const float* __restrict__ X,
                                                   const unsigned short* __restrict__ W1T,
                                                   const float* __restrict__ b1,
                                                   unsigned short* __restrict__ X0,
                                                   int nct) {
    int tid = threadIdx.x;
    int wid = tid >> 6, lane = tid & 63;
    int m = lane & 15, quad = lane >> 4;
    int rowA = blockIdx.x * 64 + wid * 16 + m;
    int rowc = rowA < N_NODES ? rowA : N_NODES - 1;
    bf16x8 af[8];
    const float* ap = X + (size_t)rowc * F_IN_D + quad * 8;
    #pragma unroll
    for (int s = 0; s < 8; ++s) {
        float4 lo = *(const float4*)(ap + s * 32);
        float4 hi = *(const float4*)(ap + s * 32 + 4);
        union { unsigned short u[8]; bf16x8 v; } pk;
        pk.u[0] = f2bf(lo.x); pk.u[1] = f2bf(lo.y);
        pk.u[2] = f2bf(lo.z); pk.u[3] = f2bf(lo.w);
        pk.u[4] = f2bf(hi.x); pk.u[5] = f2bf(hi.y);
        pk.u[6] = f2bf(hi.z); pk.u[7] = f2bf(hi.w);
        af[s] = pk.v;
    }
    int row0 = blockIdx.x * 64 + wid * 16 + quad * 4;
    for (int ct = 0; ct < nct; ++ct) {
        int col = ct * 16 + m;
        const unsigned short* bp = W1T + (size_t)col * F_IN_D + quad * 8;
        f32x4 acc = {0.f, 0.f, 0.f, 0.f};
        #pragma unroll
        for (int s = 0; s < 8; ++s) {
            bf16x8 bfr = __builtin_bit_cast(bf16x8, *(const uint4*)(bp + s * 32));
            acc = __builtin_amdgcn_mfma_f32_16x16x32_bf16(af[s], bfr, acc, 0, 0, 0);
        }
        float bb = b1[col];
        #pragma unroll
        for (int rg = 0; rg < 4; ++rg) {
            int r = row0 + rg;
            if (r < N_NODES)
                X0[(size_t)r * H_DIM + col] = f2bf(fmaxf(acc[rg] + bb, 0.f));
        }
    }
}

// ---------------- MFMA fused QKV projection (dual-accumulator interleave) ------
// R16 form RESTORED: grid = (1+2t)*TILES_N, separate K and V blocks.
// R17's K+V-share-A fusion REGRESSED (+17 us): it halved the grid (4.3 -> 2.45
// waves/SIMD at t=3) while doubling per-block serial work -- these blocks are
// latency-bound, wave-parallelism wins. Q: bf16 out; K/V: fp8 e4m3
// [node][slice(3)][128]. nct RUNTIME (=4 col-pairs); B-preload also REGRESSED
// (R13/R14) -- keep loop form.

__global__ __launch_bounds__(256) void k_qkv_mfma(const unsigned short* __restrict__ XHb,
                                                  const unsigned short* __restrict__ WTq,
                                                  const unsigned short* __restrict__ WTk,
                                                  const unsigned short* __restrict__ WTv,
                                                  const float* __restrict__ bq,
                                                  const float* __restrict__ bk,
                                                  const float* __restrict__ bv,
                                                  unsigned short* __restrict__ Qb,
                                                  unsigned char* __restrict__ Kb,
                                                  unsigned char* __restrict__ Vb,
                                                  int l, int t, int nct) {
    int tid = threadIdx.x;
    int wid = tid >> 6, lane = tid & 63;
    int m = lane & 15, quad = lane >> 4;
    int mi = blockIdx.x / TILES_N;
    int rt = blockIdx.x % TILES_N;
    const unsigned short* WT; const float* bias; int slice, mode;
    if (mi == 0)      { WT = WTq; bias = bq; slice = l;          mode = 0; }
    else if (mi <= t) { WT = WTk; bias = bk; slice = mi - 1;     mode = 1; }
    else              { WT = WTv; bias = bv; slice = mi - t - 1; mode = 2; }
    const unsigned short* A = XHb + (size_t)slice * N_NODES * H_DIM;
    int rowA = rt * 64 + wid * 16 + m;
    bf16x8 af[4];
    const unsigned short* ap = A + (size_t)rowA * H_DIM + quad * 8;
    #pragma unroll
    for (int s = 0; s < 4; ++s)
        af[s] = __builtin_bit_cast(bf16x8, *(const uint4*)(ap + s * 32));
    int row0 = rt * 64 + wid * 16 + quad * 4;
    unsigned char* OutB = (mode == 1) ? Kb : Vb;
    for (int cp = 0; cp < nct; ++cp) {
        int colA = cp * 32 + m;
        int colB = colA + 16;
        const unsigned short* bpA = WT + (size_t)colA * H_DIM + quad * 8;
        const unsigned short* bpB = WT + (size_t)colB * H_DIM + quad * 8;
        bf16x8 bA[4], bB[4];
        #pragma unroll
        for (int s = 0; s < 4; ++s) {
            bA[s] = __builtin_bit_cast(bf16x8, *(const uint4*)(bpA + s * 32));
            bB[s] = __builtin_bit_cast(bf16x8, *(const uint4*)(bpB + s * 32));
        }
        f32x4 accA = {0.f, 0.f, 0.f, 0.f};
        f32x4 accB = {0.f, 0.f, 0.f, 0.f};
        #pragma unroll
        for (int s = 0; s < 4; ++s) {
            accA = __builtin_amdgcn_mfma_f32_16x16x32_bf16(af[s], bA[s], accA, 0, 0, 0);
            accB = __builtin_amdgcn_mfma_f32_16x16x32_bf16(af[s], bB[s], accB, 0, 0, 0);
        }
        float bbA = bias[colA], bbB = bias[colB];
        #pragma unroll
        for (int rg = 0; rg < 4; ++rg) {
            int r = row0 + rg;
            if (r < N_NODES) {
                float vA = accA[rg] + bbA;
                float vB = accB[rg] + bbB;
                if (mode == 0) {
                    Qb[(size_t)r * H_DIM + colA] = f2bf(vA);
                    Qb[(size_t)r * H_DIM + colB] = f2bf(vB);
                } else {
                    OutB[((size_t)r * 3 + slice) * H_DIM + colA] = f2fp8(vA);
                    OutB[((size_t)r * 3 + slice) * H_DIM + colB] = f2fp8(vB);
                }
            }
        }
    }
}

// ---------------- fused per-node attention aggregation (wave-per-node) ----------------
// 256 threads = 4 waves = 4 nodes. fp8 K/V, 8 dims/lane (uint2), 16 lanes per
// edge -> FOUR edges per wave-iteration (quarter = lane>>4).
// L2F: final layer fuses lin2+log_softmax in the epilogue (X3 never stored;
// X row round-trips 2 KB LDS, lane c<40 computes its class dot vs W2T in L2).
// NOTE: R13's manual software pipeline REGRESSED -- keep plain loop form.

template <int T, bool L2F>
__global__ __launch_bounds__(256) void k_attn_agg(const unsigned short* __restrict__ Q,
                                                  const unsigned int* __restrict__ K,
                                                  const unsigned int* __restrict__ V,
                                                  const int* __restrict__ csr_row,
                                                  const float* __restrict__ csr_norm,
                                                  const int* __restrict__ offsets,
                                                  const int* __restrict__ degi,
                                                  unsigned int* __restrict__ Xout,
                                                  const unsigned short* __restrict__ W2T,
                                                  const float* __restrict__ b2,
                                                  float* __restrict__ out) {
    __shared__ float xrow[4][128];
    int tid = threadIdx.x;
    int wid = tid >> 6, lane = tid & 63;
    int quarter = lane >> 4, ci = lane & 15;
    int n = blockIdx.x * 4 + wid;        // grid 2500*4 == N_NODES exactly
    float q[8];
    {
        uint4 qp = *(const uint4*)&Q[(size_t)n * H_DIM + ci * 8];
        q[0] = __uint_as_float(qp.x << 16) * SCALE_F;
        q[1] = __uint_as_float(qp.x & 0xffff0000u) * SCALE_F;
        q[2] = __uint_as_float(qp.y << 16) * SCALE_F;
        q[3] = __uint_as_float(qp.y & 0xffff0000u) * SCALE_F;
        q[4] = __uint_as_float(qp.z << 16) * SCALE_F;
        q[5] = __uint_as_float(qp.z & 0xffff0000u) * SCALE_F;
        q[6] = __uint_as_float(qp.w << 16) * SCALE_F;
        q[7] = __uint_as_float(qp.w & 0xffff0000u) * SCALE_F;
    }
    int start = offsets[n];
    int cnt   = degi[n];
    int nq = (cnt + 3) >> 2;
    float a[8];
    #pragma unroll
    for (int i = 0; i < 8; ++i) a[i] = 0.f;

    for (int j = 0; j < nq; ++j) {
        int j4 = j * 4 + quarter;
        int valid = j4 < cnt;
        int idx = start + (valid ? j4 : 0);
        int   r   = csr_row[idx];
        float nrm = valid ? csr_norm[idx] : 0.f;
        const uint2* kp = (const uint2*)&K[(size_t)r * 96 + ci * 2];
        const uint2* vp = (const uint2*)&V[(size_t)r * 96 + ci * 2];
        uint2 kw[T], vw[T];
        #pragma unroll
        for (int s = 0; s < T; ++s) { kw[s] = kp[s * 16]; vw[s] = vp[s * 16]; }
        float sc[T];
        #pragma unroll
        for (int s = 0; s < T; ++s) {
            f32x2 k0 = __builtin_amdgcn_cvt_pk_f32_fp8(kw[s].x, false);
            f32x2 k1 = __builtin_amdgcn_cvt_pk_f32_fp8(kw[s].x, true);
            f32x2 k2 = __builtin_amdgcn_cvt_pk_f32_fp8(kw[s].y, false);
            f32x2 k3 = __builtin_amdgcn_cvt_pk_f32_fp8(kw[s].y, true);
            float p = q[0] * k0[0] + q[1] * k0[1] + q[2] * k1[0] + q[3] * k1[1]
                    + q[4] * k2[0] + q[5] * k2[1] + q[6] * k3[0] + q[7] * k3[1];
            p += __shfl_xor(p, 1, 2);    // head = ci>>1: pair-reduce
            sc[s] = p;
        }
        float m = 0.f;
        #pragma unroll
        for (int s = 0; s < T; ++s) m = fmaxf(m, sc[s]);
        float den = __expf(-m);          // restricted-softmax null slot
        float mv[8];
        #pragma unroll
        for (int i = 0; i < 8; ++i) mv[i] = 0.f;
        #pragma unroll
        for (int s = 0; s < T; ++s) {
            float w = __expf(sc[s] - m);
            den += w;
            f32x2 v0 = __builtin_amdgcn_cvt_pk_f32_fp8(vw[s].x, false);
            f32x2 v1 = __builtin_amdgcn_cvt_pk_f32_fp8(vw[s].x, true);
            f32x2 v2 = __builtin_amdgcn_cvt_pk_f32_fp8(vw[s].y, false);
            f32x2 v3 = __builtin_amdgcn_cvt_pk_f32_fp8(vw[s].y, true);
            mv[0] += w * v0[0]; mv[1] += w * v0[1];
            mv[2] += w * v1[0]; mv[3] += w * v1[1];
            mv[4] += w * v2[0]; mv[5] += w * v2[1];
            mv[6] += w * v3[0]; mv[7] += w * v3[1];
        }
        float ws = __fdividef(nrm, den);
        #pragma unroll
        for (int i = 0; i < 8; ++i) a[i] += ws * mv[i];
    }
    // combine the four edge-quarters
    #pragma unroll
    for (int i = 0; i < 8; ++i) {
        a[i] += __shfl_xor(a[i], 16, 64);
        a[i] += __shfl_xor(a[i], 32, 64);
    }

    if (!L2F) {
        if (quarter == 0) {
            uint4 o;
            o.x = ((unsigned int)f2bf(fmaxf(a[1], 0.f)) << 16) | (unsigned int)f2bf(fmaxf(a[0], 0.f));
            o.y = ((unsigned int)f2bf(fmaxf(a[3], 0.f)) << 16) | (unsigned int)f2bf(fmaxf(a[2], 0.f));
            o.z = ((unsigned int)f2bf(fmaxf(a[5], 0.f)) << 16) | (unsigned int)f2bf(fmaxf(a[4], 0.f));
            o.w = ((unsigned int)f2bf(fmaxf(a[7], 0.f)) << 16) | (unsigned int)f2bf(fmaxf(a[6], 0.f));
            *(uint4*)&Xout[(size_t)n * 64 + ci * 4] = o;   // relu, packed bf16
        }
    } else {
        // fused lin2 + log_softmax; X3 never materialized
        if (quarter == 0) {
            #pragma unroll
            for (int i = 0; i < 8; ++i) xrow[wid][ci * 8 + i] = fmaxf(a[i], 0.f);
        }
        __syncthreads();
        const float* xr = xrow[wid];
        int c = lane;
        int cw = (c < 48) ? c : 0;
        const unsigned short* wr = W2T + (size_t)cw * H_DIM;
        float acc = (c < C_OUTD) ? b2[c] : 0.f;
        for (int k0 = 0; k0 < H_DIM; k0 += 8) {
            uint4 wv4 = *(const uint4*)(wr + k0);
            float4 x0 = *(const float4*)&xr[k0];
            float4 x1 = *(const float4*)&xr[k0 + 4];
            acc += x0.x * __uint_as_float(wv4.x << 16)
                 + x0.y * __uint_as_float(wv4.x & 0xffff0000u)
                 + x0.z * __uint_as_float(wv4.y << 16)
                 + x0.w * __uint_as_float(wv4.y & 0xffff0000u)
                 + x1.x * __uint_as_float(wv4.z << 16)
                 + x1.y * __uint_as_float(wv4.z & 0xffff0000u)
                 + x1.z * __uint_as_float(wv4.w << 16)
                 + x1.w * __uint_as_float(wv4.w & 0xffff0000u);
        }
        float lg = (c < C_OUTD) ? acc : -INFINITY;
        float mx = lg;
        #pragma unroll
        for (int o = 32; o > 0; o >>= 1) mx = fmaxf(mx, __shfl_xor(mx, o, 64));
        float e = (c < C_OUTD) ? __expf(lg - mx) : 0.f;
        float sm = e;
        #pragma unroll
        for (int o = 32; o > 0; o >>= 1) sm += __shfl_xor(sm, o, 64);
        float lse = mx + __logf(sm);
        if (c < C_OUTD) out[(size_t)n * C_OUTD + c] = lg - lse;
    }
}

// ---------------- launcher ----------------

extern "C" void kernel_launch(void* const* d_in, const int* in_sizes, int n_in,
                              void* d_out, int out_size, void* d_ws, size_t ws_size,
                              hipStream_t stream) {
    const int*   ei      = (const int*)d_in[0];
    const int*   row     = ei;
    const int*   col     = ei + NEDGES;
    const float* x_param = (const float*)d_in[1];
    const float* lin1_w  = (const float*)d_in[2];
    const float* lin1_b  = (const float*)d_in[3];
    const float* wq      = (const float*)d_in[4];
    const float* wk      = (const float*)d_in[5];
    const float* wv      = (const float*)d_in[6];
    const float* bq      = (const float*)d_in[7];
    const float* bk      = (const float*)d_in[8];
    const float* bv      = (const float*)d_in[9];
    const float* lin2_w  = (const float*)d_in[10];
    const float* lin2_b  = (const float*)d_in[11];
    float*       out     = (float*)d_out;

    char* wbase = (char*)d_ws;
    size_t off = 0;
    auto alloc = [&](size_t bytes) -> void* {
        off = (off + 255) & ~(size_t)255;
        void* p = wbase + off;
        off += bytes;
        return p;
    };
    int*            degi     = (int*)           alloc((size_t)N_NODES * 4);
    int*            offsets  = (int*)           alloc((size_t)N_NODES * 4);
    int*            cursor   = (int*)           alloc((size_t)N_NODES * 4);
    int*            csr_row  = (int*)           alloc((size_t)ETOT * 4);
    float*          csr_norm = (float*)         alloc((size_t)ETOT * 4);
    unsigned short* W1T      = (unsigned short*)alloc((size_t)H_DIM * F_IN_D * 2);
    unsigned short* WTq      = (unsigned short*)alloc((size_t)3 * H_DIM * H_DIM * 2);
    unsigned short* WTk      = (unsigned short*)alloc((size_t)3 * H_DIM * H_DIM * 2);
    unsigned short* WTv      = (unsigned short*)alloc((size_t)3 * H_DIM * H_DIM * 2);
    unsigned short* W2T      = (unsigned short*)alloc((size_t)48 * H_DIM * 2);
    unsigned short* XHb      = (unsigned short*)alloc((size_t)4 * N_NODES * H_DIM * 2);
    unsigned short* Qb       = (unsigned short*)alloc((size_t)N_NODES * H_DIM * 2);
    unsigned char*  Kb       = (unsigned char*) alloc((size_t)N_NODES * 3 * H_DIM);
    unsigned char*  Vb       = (unsigned char*) alloc((size_t)N_NODES * 3 * H_DIM);

    // fused prep: weight casts + deg init
    k_prep<<<768, 256, 0, stream>>>(lin1_w, wq, wk, wv, lin2_w,
                                    W1T, WTq, WTk, WTv, W2T, degi);
    k_deg_count<<<(NEDGES + 255) / 256, 256, 0, stream>>>(col, degi);
    k_scan     <<<1, 256, 0, stream>>>(degi, offsets, cursor);
    k_scatter  <<<(ETOT + 255) / 256, 256, 0, stream>>>(row, col, degi, offsets, cursor,
                                                        csr_row, csr_norm);

    // x0 = relu(x @ W1 + b1)  [MFMA, fp32 in (cast fused), bf16 out]
    k_lin1_mfma<<<TILES_N, 256, 0, stream>>>(x_param, W1T, lin1_b, XHb, 8);

    for (int l = 0; l < 3; ++l) {
        int t = l + 1;
        k_qkv_mfma<<<(1 + 2 * t) * TILES_N, 256, 0, stream>>>(
            XHb, WTq + (size_t)l * 16384, WTk + (size_t)l * 16384, WTv + (size_t)l * 16384,
            bq + l * H_DIM, bk + l * H_DIM, bv + l * H_DIM,
            Qb, Kb, Vb, l, t, 4);
        unsigned int* Xnext = (unsigned int*)(XHb + (size_t)(l + 1) * N_NODES * H_DIM);
        if (t == 1)
            k_attn_agg<1, false><<<2500, 256, 0, stream>>>(
                Qb, (const unsigned int*)Kb, (const unsigned int*)Vb, csr_row,
                csr_norm, offsets, degi, Xnext, W2T, lin2_b, out);
        else if (t == 2)
            k_attn_agg<2, false><<<2500, 256, 0, stream>>>(
                Qb, (const unsigned int*)Kb, (const unsigned int*)Vb, csr_row,
                csr_norm, offsets, degi, Xnext, W2T, lin2_b, out);
        else
            k_attn_agg<3, true><<<2500, 256, 0, stream>>>(
                Qb, (const unsigned int*)Kb, (const unsigned int*)Vb, csr_row,
                csr_norm, offsets, degi, Xnext, W2T, lin2_b, out);
    }
}

// Round 19
// 257.638 us; speedup vs baseline: 1.0696x; 1.0383x over previous
//
#include <hip/hip_runtime.h>
#include <math.h>

#define N_NODES 10000
#define F_IN_D  256
#define H_DIM   128
#define C_OUTD  40
#define NHEADS  8
#define NEDGES  160000
#define ETOT    (NEDGES + N_NODES)
#define SCALE_F 0.25f  /* 1/sqrt(16) */
#define TILES_N 157    /* ceil(10000/64) */

typedef __attribute__((ext_vector_type(8))) short bf16x8;   // 8 bf16 = 4 VGPRs
typedef __attribute__((ext_vector_type(4))) float f32x4;
typedef __attribute__((ext_vector_type(2))) float f32x2;

__device__ __forceinline__ unsigned short f2bf(float f) {
    unsigned int u = __float_as_uint(f);
    unsigned int r = (u + 0x7FFFu + ((u >> 16) & 1u)) >> 16;  // RNE
    return (unsigned short)r;
}
__device__ __forceinline__ float bf2f(unsigned short h) {
    return __uint_as_float(((unsigned int)h) << 16);
}
__device__ __forceinline__ unsigned char f2fp8(float v) {
    int pk = __builtin_amdgcn_cvt_pk_fp8_f32(v, v, 0, false);  // OCP e4m3fn
    return (unsigned char)(pk & 0xff);
}

// ---------------- graph preprocessing ----------------

__global__ void k_deg_count(const int* __restrict__ col, int* degi) {
    int e = blockIdx.x * 256 + threadIdx.x;
    if (e < NEDGES) atomicAdd(&degi[col[e]], 1);
}

__global__ void k_scan(const int* __restrict__ degi, int* offsets, int* cursor) {
    __shared__ int part[256];
    int tid = threadIdx.x;
    int s = 0;
    if (tid < 250) {
        const int4* d4 = (const int4*)degi;
        for (int i = 0; i < 10; ++i) {
            int4 v = d4[tid * 10 + i];
            s += v.x + v.y + v.z + v.w;
        }
    }
    part[tid] = s;
    __syncthreads();
    for (int off = 1; off < 256; off <<= 1) {
        int v = 0;
        if (tid >= off) v = part[tid - off];
        __syncthreads();
        part[tid] += v;
        __syncthreads();
    }
    if (tid < 250) {
        int base = part[tid] - s;  // exclusive prefix
        int beg = tid * 40;
        for (int i = 0; i < 40; ++i) {
            offsets[beg + i] = base;
            cursor[beg + i]  = 0;
            base += degi[beg + i];
        }
    }
}

__global__ void k_scatter(const int* __restrict__ row, const int* __restrict__ col,
                          const int* __restrict__ degi, const int* __restrict__ offsets,
                          int* cursor, int* csr_row, float* csr_norm) {
    int e = blockIdx.x * 256 + threadIdx.x;
    if (e >= ETOT) return;
    int r, c;
    if (e < NEDGES) { r = row[e]; c = col[e]; }
    else            { r = c = e - NEDGES; }   // self-loop
    int slot = offsets[c] + atomicAdd(&cursor[c], 1);
    float dr = rsqrtf((float)degi[r]);
    float dc = rsqrtf((float)degi[c]);
    csr_row[slot]  = r;
    csr_norm[slot] = dr * dc;
}

// ---------------- fused prep: weight casts + deg_init ----------------

__global__ void k_prep(const float* __restrict__ w1, const float* __restrict__ wq,
                       const float* __restrict__ wk, const float* __restrict__ wv,
                       const float* __restrict__ w2,
                       unsigned short* __restrict__ W1T, unsigned short* __restrict__ WTq,
                       unsigned short* __restrict__ WTk, unsigned short* __restrict__ WTv,
                       unsigned short* __restrict__ W2T, int* __restrict__ degi) {
    int b = blockIdx.x;
    if (b < 728) {
        int e = b * 256 + threadIdx.x;
        if (e < 32768) {
            int n = e >> 8, k = e & 255;
            W1T[e] = f2bf(w1[k * H_DIM + n]);
        } else if (e < 180224) {
            int e2 = e - 32768;
            int mat = e2 >> 14;          // 0..8
            int r   = e2 & 16383;
            int n = r >> 7, k = r & 127;
            int l = mat / 3, ws = mat % 3;
            const float*    src = (ws == 0) ? wq  : (ws == 1) ? wk  : wv;
            unsigned short* dst = (ws == 0) ? WTq : (ws == 1) ? WTk : WTv;
            dst[l * 16384 + n * H_DIM + k] = f2bf(src[l * 16384 + k * H_DIM + n]);
        } else if (e < 186368) {
            int e3 = e - 180224;
            int c = e3 >> 7, k = e3 & 127;
            W2T[c * H_DIM + k] = (c < C_OUTD) ? f2bf(w2[k * C_OUTD + c]) : 0;
        }
    } else {
        int i = (b - 728) * 256 + threadIdx.x;
        if (i < N_NODES) degi[i] = 1;    // self-loop
    }
}

// ---------------- MFMA lin1: X0 = relu(x @ W1 + b1), fp32 in, bf16 out ---------
// Reads x_param fp32 directly (cast fused). rowA CLAMPED (input buffer).
// nct RUNTIME arg (=8): prevents full-unroll spill.

__global__ __launch_bounds__(256) void k_lin1_mfma(const float* __restrict__ X,
                                                   const unsigned short* __restrict__ W1T,
                                                   const float* __restrict__ b1,
                                                   unsigned short* __restrict__ X0,
                                                   int nct) {
    int tid = threadIdx.x;
    int wid = tid >> 6, lane = tid & 63;
    int m = lane & 15, quad = lane >> 4;
    int rowA = blockIdx.x * 64 + wid * 16 + m;
    int rowc = rowA < N_NODES ? rowA : N_NODES - 1;
    bf16x8 af[8];
    const float* ap = X + (size_t)rowc * F_IN_D + quad * 8;
    #pragma unroll
    for (int s = 0; s < 8; ++s) {
        float4 lo = *(const float4*)(ap + s * 32);
        float4 hi = *(const float4*)(ap + s * 32 + 4);
        union { unsigned short u[8]; bf16x8 v; } pk;
        pk.u[0] = f2bf(lo.x); pk.u[1] = f2bf(lo.y);
        pk.u[2] = f2bf(lo.z); pk.u[3] = f2bf(lo.w);
        pk.u[4] = f2bf(hi.x); pk.u[5] = f2bf(hi.y);
        pk.u[6] = f2bf(hi.z); pk.u[7] = f2bf(hi.w);
        af[s] = pk.v;
    }
    int row0 = blockIdx.x * 64 + wid * 16 + quad * 4;
    for (int ct = 0; ct < nct; ++ct) {
        int col = ct * 16 + m;
        const unsigned short* bp = W1T + (size_t)col * F_IN_D + quad * 8;
        f32x4 acc = {0.f, 0.f, 0.f, 0.f};
        #pragma unroll
        for (int s = 0; s < 8; ++s) {
            bf16x8 bfr = __builtin_bit_cast(bf16x8, *(const uint4*)(bp + s * 32));
            acc = __builtin_amdgcn_mfma_f32_16x16x32_bf16(af[s], bfr, acc, 0, 0, 0);
        }
        float bb = b1[col];
        #pragma unroll
        for (int rg = 0; rg < 4; ++rg) {
            int r = row0 + rg;
            if (r < N_NODES)
                X0[(size_t)r * H_DIM + col] = f2bf(fmaxf(acc[rg] + bb, 0.f));
        }
    }
}

// ---------------- MFMA fused QKV projection (dual-accumulator interleave) ------
// R16 form: grid = (1+2t)*TILES_N, separate K and V blocks (K+V-share-A fusion
// REGRESSED +8 us in R17 -- latency-bound blocks want wave-parallelism).
// K/V now write an INTERLEAVED fp8 buffer: KV[node][slice][group g of 16B] =
// {K dims 8g..8g+7, V dims 8g..8g+7} -- lets attn fetch K+V with ONE uint4.
// Q: bf16. nct RUNTIME (=4 col-pairs); B-preload REGRESSED (R13/R14).

__global__ __launch_bounds__(256) void k_qkv_mfma(const unsigned short* __restrict__ XHb,
                                                  const unsigned short* __restrict__ WTq,
                                                  const unsigned short* __restrict__ WTk,
                                                  const unsigned short* __restrict__ WTv,
                                                  const float* __restrict__ bq,
                                                  const float* __restrict__ bk,
                                                  const float* __restrict__ bv,
                                                  unsigned short* __restrict__ Qb,
                                                  unsigned char* __restrict__ KVb,
                                                  int l, int t, int nct) {
    int tid = threadIdx.x;
    int wid = tid >> 6, lane = tid & 63;
    int m = lane & 15, quad = lane >> 4;
    int mi = blockIdx.x / TILES_N;
    int rt = blockIdx.x % TILES_N;
    const unsigned short* WT; const float* bias; int slice, mode;
    if (mi == 0)      { WT = WTq; bias = bq; slice = l;          mode = 0; }
    else if (mi <= t) { WT = WTk; bias = bk; slice = mi - 1;     mode = 1; }
    else              { WT = WTv; bias = bv; slice = mi - t - 1; mode = 2; }
    const unsigned short* A = XHb + (size_t)slice * N_NODES * H_DIM;
    int rowA = rt * 64 + wid * 16 + m;
    bf16x8 af[4];
    const unsigned short* ap = A + (size_t)rowA * H_DIM + quad * 8;
    #pragma unroll
    for (int s = 0; s < 4; ++s)
        af[s] = __builtin_bit_cast(bf16x8, *(const uint4*)(ap + s * 32));
    int row0 = rt * 64 + wid * 16 + quad * 4;
    int vofs = (mode == 2) ? 8 : 0;      // V occupies the upper 8 bytes of each 16B group
    for (int cp = 0; cp < nct; ++cp) {
        int colA = cp * 32 + m;
        int colB = colA + 16;
        const unsigned short* bpA = WT + (size_t)colA * H_DIM + quad * 8;
        const unsigned short* bpB = WT + (size_t)colB * H_DIM + quad * 8;
        bf16x8 bA[4], bB[4];
        #pragma unroll
        for (int s = 0; s < 4; ++s) {
            bA[s] = __builtin_bit_cast(bf16x8, *(const uint4*)(bpA + s * 32));
            bB[s] = __builtin_bit_cast(bf16x8, *(const uint4*)(bpB + s * 32));
        }
        f32x4 accA = {0.f, 0.f, 0.f, 0.f};
        f32x4 accB = {0.f, 0.f, 0.f, 0.f};
        #pragma unroll
        for (int s = 0; s < 4; ++s) {
            accA = __builtin_amdgcn_mfma_f32_16x16x32_bf16(af[s], bA[s], accA, 0, 0, 0);
            accB = __builtin_amdgcn_mfma_f32_16x16x32_bf16(af[s], bB[s], accB, 0, 0, 0);
        }
        float bbA = bias[colA], bbB = bias[colB];
        #pragma unroll
        for (int rg = 0; rg < 4; ++rg) {
            int r = row0 + rg;
            if (r < N_NODES) {
                float vA = accA[rg] + bbA;
                float vB = accB[rg] + bbB;
                if (mode == 0) {
                    Qb[(size_t)r * H_DIM + colA] = f2bf(vA);
                    Qb[(size_t)r * H_DIM + colB] = f2bf(vB);
                } else {
                    size_t nb = ((size_t)r * 3 + slice) * 256;
                    KVb[nb + (colA >> 3) * 16 + (colA & 7) + vofs] = f2fp8(vA);
                    KVb[nb + (colB >> 3) * 16 + (colB & 7) + vofs] = f2fp8(vB);
                }
            }
        }
    }
}

// ---------------- fused per-node attention aggregation (wave-per-node) ----------------
// 256 threads = 4 waves = 4 nodes. Interleaved fp8 KV: one uint4/lane/slice
// fetches 8 K-dims (.xy) AND 8 V-dims (.zw) -- 3 loads per edge (was 6).
// 16 lanes per edge -> FOUR edges per wave-iteration (quarter = lane>>4).
// KV layout: [node][slice(3)][256B]. Q: bf16.
// NOTE: R13 pipeline, R17 K+V-block fusion, R17/R18 lin2-fusion all REGRESSED.

template <int T>
__global__ __launch_bounds__(256) void k_attn_agg(const unsigned short* __restrict__ Q,
                                                  const uint4* __restrict__ KV,
                                                  const int* __restrict__ csr_row,
                                                  const float* __restrict__ csr_norm,
                                                  const int* __restrict__ offsets,
                                                  const int* __restrict__ degi,
                                                  unsigned int* __restrict__ Xout) {
    int tid = threadIdx.x;
    int wid = tid >> 6, lane = tid & 63;
    int quarter = lane >> 4, ci = lane & 15;
    int n = blockIdx.x * 4 + wid;        // grid 2500*4 == N_NODES exactly
    float q[8];
    {
        uint4 qp = *(const uint4*)&Q[(size_t)n * H_DIM + ci * 8];
        q[0] = __uint_as_float(qp.x << 16) * SCALE_F;
        q[1] = __uint_as_float(qp.x & 0xffff0000u) * SCALE_F;
        q[2] = __uint_as_float(qp.y << 16) * SCALE_F;
        q[3] = __uint_as_float(qp.y & 0xffff0000u) * SCALE_F;
        q[4] = __uint_as_float(qp.z << 16) * SCALE_F;
        q[5] = __uint_as_float(qp.z & 0xffff0000u) * SCALE_F;
        q[6] = __uint_as_float(qp.w << 16) * SCALE_F;
        q[7] = __uint_as_float(qp.w & 0xffff0000u) * SCALE_F;
    }
    int start = offsets[n];
    int cnt   = degi[n];
    int nq = (cnt + 3) >> 2;
    float a[8];
    #pragma unroll
    for (int i = 0; i < 8; ++i) a[i] = 0.f;

    for (int j = 0; j < nq; ++j) {
        int j4 = j * 4 + quarter;
        int valid = j4 < cnt;
        int idx = start + (valid ? j4 : 0);
        int   r   = csr_row[idx];
        float nrm = valid ? csr_norm[idx] : 0.f;
        // KV uint4 index: node r, slice s, group ci  ->  r*48 + s*16 + ci
        const uint4* kvp = KV + (size_t)r * 48 + ci;
        uint4 kv[T];
        #pragma unroll
        for (int s = 0; s < T; ++s) kv[s] = kvp[s * 16];
        float sc[T];
        #pragma unroll
        for (int s = 0; s < T; ++s) {
            f32x2 k0 = __builtin_amdgcn_cvt_pk_f32_fp8(kv[s].x, false);
            f32x2 k1 = __builtin_amdgcn_cvt_pk_f32_fp8(kv[s].x, true);
            f32x2 k2 = __builtin_amdgcn_cvt_pk_f32_fp8(kv[s].y, false);
            f32x2 k3 = __builtin_amdgcn_cvt_pk_f32_fp8(kv[s].y, true);
            float p = q[0] * k0[0] + q[1] * k0[1] + q[2] * k1[0] + q[3] * k1[1]
                    + q[4] * k2[0] + q[5] * k2[1] + q[6] * k3[0] + q[7] * k3[1];
            p += __shfl_xor(p, 1, 2);    // head = ci>>1: pair-reduce
            sc[s] = p;
        }
        float m = 0.f;
        #pragma unroll
        for (int s = 0; s < T; ++s) m = fmaxf(m, sc[s]);
        float den = __expf(-m);          // restricted-softmax null slot
        float mv[8];
        #pragma unroll
        for (int i = 0; i < 8; ++i) mv[i] = 0.f;
        #pragma unroll
        for (int s = 0; s < T; ++s) {
            float w = __expf(sc[s] - m);
            den += w;
            f32x2 v0 = __builtin_amdgcn_cvt_pk_f32_fp8(kv[s].z, false);
            f32x2 v1 = __builtin_amdgcn_cvt_pk_f32_fp8(kv[s].z, true);
            f32x2 v2 = __builtin_amdgcn_cvt_pk_f32_fp8(kv[s].w, false);
            f32x2 v3 = __builtin_amdgcn_cvt_pk_f32_fp8(kv[s].w, true);
            mv[0] += w * v0[0]; mv[1] += w * v0[1];
            mv[2] += w * v1[0]; mv[3] += w * v1[1];
            mv[4] += w * v2[0]; mv[5] += w * v2[1];
            mv[6] += w * v3[0]; mv[7] += w * v3[1];
        }
        float ws = __fdividef(nrm, den);
        #pragma unroll
        for (int i = 0; i < 8; ++i) a[i] += ws * mv[i];
    }
    // combine the four edge-quarters
    #pragma unroll
    for (int i = 0; i < 8; ++i) {
        a[i] += __shfl_xor(a[i], 16, 64);
        a[i] += __shfl_xor(a[i], 32, 64);
    }
    if (quarter == 0) {
        uint4 o;
        o.x = ((unsigned int)f2bf(fmaxf(a[1], 0.f)) << 16) | (unsigned int)f2bf(fmaxf(a[0], 0.f));
        o.y = ((unsigned int)f2bf(fmaxf(a[3], 0.f)) << 16) | (unsigned int)f2bf(fmaxf(a[2], 0.f));
        o.z = ((unsigned int)f2bf(fmaxf(a[5], 0.f)) << 16) | (unsigned int)f2bf(fmaxf(a[4], 0.f));
        o.w = ((unsigned int)f2bf(fmaxf(a[7], 0.f)) << 16) | (unsigned int)f2bf(fmaxf(a[6], 0.f));
        *(uint4*)&Xout[(size_t)n * 64 + ci * 4] = o;   // relu, packed bf16
    }
}

// ---------------- MFMA lin2 + fused log_softmax (standalone -- fusion into
// attn REGRESSED +8.6 us in R18) ----------------

__global__ __launch_bounds__(256) void k_lin2_mfma(const unsigned short* __restrict__ X,
                                                   const unsigned short* __restrict__ W2T,
                                                   const float* __restrict__ b2,
                                                   float* __restrict__ out) {
    int tid = threadIdx.x;
    int wid = tid >> 6, lane = tid & 63;
    int m = lane & 15, quad = lane >> 4;
    int rowA = blockIdx.x * 64 + wid * 16 + m;      // overread past N_NODES stays in ws
    bf16x8 af[4];
    const unsigned short* ap = X + (size_t)rowA * H_DIM + quad * 8;
    #pragma unroll
    for (int s = 0; s < 4; ++s)
        af[s] = __builtin_bit_cast(bf16x8, *(const uint4*)(ap + s * 32));

    f32x4 acc0 = {0.f, 0.f, 0.f, 0.f};
    f32x4 acc1 = {0.f, 0.f, 0.f, 0.f};
    f32x4 acc2 = {0.f, 0.f, 0.f, 0.f};
    const unsigned short* bp0 = W2T + (size_t)(m)      * H_DIM + quad * 8;
    const unsigned short* bp1 = W2T + (size_t)(16 + m) * H_DIM + quad * 8;
    const unsigned short* bp2 = W2T + (size_t)(32 + m) * H_DIM + quad * 8;
    #pragma unroll
    for (int s = 0; s < 4; ++s) {
        bf16x8 b0 = __builtin_bit_cast(bf16x8, *(const uint4*)(bp0 + s * 32));
        acc0 = __builtin_amdgcn_mfma_f32_16x16x32_bf16(af[s], b0, acc0, 0, 0, 0);
        bf16x8 b1 = __builtin_bit_cast(bf16x8, *(const uint4*)(bp1 + s * 32));
        acc1 = __builtin_amdgcn_mfma_f32_16x16x32_bf16(af[s], b1, acc1, 0, 0, 0);
        bf16x8 b2f = __builtin_bit_cast(bf16x8, *(const uint4*)(bp2 + s * 32));
        acc2 = __builtin_amdgcn_mfma_f32_16x16x32_bf16(af[s], b2f, acc2, 0, 0, 0);
    }

    float bb0 = b2[m], bb1 = b2[16 + m];
    float bb2 = (m < 8) ? b2[32 + m] : 0.f;
    int row0 = blockIdx.x * 64 + wid * 16 + quad * 4;
    #pragma unroll
    for (int rg = 0; rg < 4; ++rg) {
        int r = row0 + rg;
        float v0 = acc0[rg] + bb0;
        float v1 = acc1[rg] + bb1;
        float v2 = (m < 8) ? (acc2[rg] + bb2) : -INFINITY;
        float mx = fmaxf(fmaxf(v0, v1), v2);
        #pragma unroll
        for (int o = 8; o > 0; o >>= 1) mx = fmaxf(mx, __shfl_xor(mx, o, 16));
        float sm = __expf(v0 - mx) + __expf(v1 - mx) + ((m < 8) ? __expf(v2 - mx) : 0.f);
        #pragma unroll
        for (int o = 8; o > 0; o >>= 1) sm += __shfl_xor(sm, o, 16);
        float lse = mx + __logf(sm);
        if (r < N_NODES) {
            out[(size_t)r * C_OUTD + m]      = v0 - lse;
            out[(size_t)r * C_OUTD + 16 + m] = v1 - lse;
            if (m < 8) out[(size_t)r * C_OUTD + 32 + m] = v2 - lse;
        }
    }
}

// ---------------- launcher ----------------

extern "C" void kernel_launch(void* const* d_in, const int* in_sizes, int n_in,
                              void* d_out, int out_size, void* d_ws, size_t ws_size,
                              hipStream_t stream) {
    const int*   ei      = (const int*)d_in[0];
    const int*   row     = ei;
    const int*   col     = ei + NEDGES;
    const float* x_param = (const float*)d_in[1];
    const float* lin1_w  = (const float*)d_in[2];
    const float* lin1_b  = (const float*)d_in[3];
    const float* wq      = (const float*)d_in[4];
    const float* wk      = (const float*)d_in[5];
    const float* wv      = (const float*)d_in[6];
    const float* bq      = (const float*)d_in[7];
    const float* bk      = (const float*)d_in[8];
    const float* bv      = (const float*)d_in[9];
    const float* lin2_w  = (const float*)d_in[10];
    const float* lin2_b  = (const float*)d_in[11];
    float*       out     = (float*)d_out;

    char* wbase = (char*)d_ws;
    size_t off = 0;
    auto alloc = [&](size_t bytes) -> void* {
        off = (off + 255) & ~(size_t)255;
        void* p = wbase + off;
        off += bytes;
        return p;
    };
    int*            degi     = (int*)           alloc((size_t)N_NODES * 4);
    int*            offsets  = (int*)           alloc((size_t)N_NODES * 4);
    int*            cursor   = (int*)           alloc((size_t)N_NODES * 4);
    int*            csr_row  = (int*)           alloc((size_t)ETOT * 4);
    float*          csr_norm = (float*)         alloc((size_t)ETOT * 4);
    unsigned short* W1T      = (unsigned short*)alloc((size_t)H_DIM * F_IN_D * 2);
    unsigned short* WTq      = (unsigned short*)alloc((size_t)3 * H_DIM * H_DIM * 2);
    unsigned short* WTk      = (unsigned short*)alloc((size_t)3 * H_DIM * H_DIM * 2);
    unsigned short* WTv      = (unsigned short*)alloc((size_t)3 * H_DIM * H_DIM * 2);
    unsigned short* W2T      = (unsigned short*)alloc((size_t)48 * H_DIM * 2);
    unsigned short* XHb      = (unsigned short*)alloc((size_t)4 * N_NODES * H_DIM * 2);
    unsigned short* Qb       = (unsigned short*)alloc((size_t)N_NODES * H_DIM * 2);
    unsigned char*  KVb      = (unsigned char*) alloc((size_t)N_NODES * 3 * 256);

    // fused prep: weight casts + deg init
    k_prep<<<768, 256, 0, stream>>>(lin1_w, wq, wk, wv, lin2_w,
                                    W1T, WTq, WTk, WTv, W2T, degi);
    k_deg_count<<<(NEDGES + 255) / 256, 256, 0, stream>>>(col, degi);
    k_scan     <<<1, 256, 0, stream>>>(degi, offsets, cursor);
    k_scatter  <<<(ETOT + 255) / 256, 256, 0, stream>>>(row, col, degi, offsets, cursor,
                                                        csr_row, csr_norm);

    // x0 = relu(x @ W1 + b1)  [MFMA, fp32 in (cast fused), bf16 out]
    k_lin1_mfma<<<TILES_N, 256, 0, stream>>>(x_param, W1T, lin1_b, XHb, 8);

    for (int l = 0; l < 3; ++l) {
        int t = l + 1;
        k_qkv_mfma<<<(1 + 2 * t) * TILES_N, 256, 0, stream>>>(
            XHb, WTq + (size_t)l * 16384, WTk + (size_t)l * 16384, WTv + (size_t)l * 16384,
            bq + l * H_DIM, bk + l * H_DIM, bv + l * H_DIM,
            Qb, KVb, l, t, 4);
        unsigned int* Xnext = (unsigned int*)(XHb + (size_t)(l + 1) * N_NODES * H_DIM);
        if (t == 1)
            k_attn_agg<1><<<2500, 256, 0, stream>>>(Qb, (const uint4*)KVb, csr_row,
                                                    csr_norm, offsets, degi, Xnext);
        else if (t == 2)
            k_attn_agg<2><<<2500, 256, 0, stream>>>(Qb, (const uint4*)KVb, csr_row,
                                                    csr_norm, offsets, degi, Xnext);
        else
            k_attn_agg<3><<<2500, 256, 0, stream>>>(Qb, (const uint4*)KVb, csr_row,
                                                    csr_norm, offsets, degi, Xnext);
    }

    k_lin2_mfma<<<TILES_N, 256, 0, stream>>>(XHb + (size_t)3 * N_NODES * H_DIM,
                                             W2T, lin2_b, out);
}